// Round 19
// baseline (235.064 us; speedup 1.0000x reference)
//
#include <hip/hip_runtime.h>
#include <hip/hip_bf16.h>
#include <cstdint>
#include <cstddef>

#define NN 50000
#define NE 800000
#define INC 128
#define HIDC 256
#define NH 4
#define OUTC 40
#define CAP 64   // bucket capacity; deg ~ Poisson(16), P(>=64) ~ e^-125

#define GE_BLOCKS ((NE + 255)/256)          // 3125
#define CVT_BLOCKS ((HIDC*INC/4 + 255)/256) // 32
#define FZ_BLOCKS ((NN + 255)/256)          // 196
#define G1_BLOCKS ((NN + 63)/64)            // 782

typedef __attribute__((ext_vector_type(8))) short short8_t;
typedef __attribute__((ext_vector_type(4))) float f32x4_t;

__device__ __forceinline__ float lrelu(float x){ return x > 0.f ? x : 0.2f*x; }
__device__ __forceinline__ unsigned short bfr(float f){
  __hip_bfloat16 h = __float2bfloat16(f);
  return *reinterpret_cast<unsigned short*>(&h);
}
__device__ __forceinline__ float bflo(unsigned u){ return __uint_as_float(u << 16); }
__device__ __forceinline__ float bfhi(unsigned u){ return __uint_as_float(u & 0xffff0000u); }

// Per-block dtype probe: int64 view of int32 pairs gives values >= 2^32 at some
// of 64 strided samples. Wave 0 probes, result broadcast via LDS.
__device__ __forceinline__ int probe_flag(const void* ei, int tid, int* sflag){
  if (tid < 64){
    long long v = ((const long long*)ei)[(long long)tid * (NE/64)];
    bool ok = (v >= 0) && (v < NN);
    unsigned long long m = __ballot(ok);
    if (tid == 0) *sflag = (m == 0xFFFFFFFFFFFFFFFFull) ? 1 : 0;
  }
  __syncthreads();
  return *sflag;
}

// ---- prep: W1->bf16 convert + zero bucket counters, one dispatch ----
__global__ __launch_bounds__(256) void k_prep(const float* __restrict__ W1, unsigned short* __restrict__ w1b,
                                              int* __restrict__ fillc){
  int tid = threadIdx.x;
  if (blockIdx.x < CVT_BLOCKS){
    int i = blockIdx.x*256 + tid;
    if (i < HIDC*INC/4){
      float4 v = ((const float4*)W1)[i];
      ushort4 o;
      o.x = bfr(v.x); o.y = bfr(v.y); o.z = bfr(v.z); o.w = bfr(v.w);
      ((ushort4*)w1b)[i] = o;
    }
    return;
  }
  int i = (blockIdx.x - CVT_BLOCKS)*256 + tid;
  if (i < NN) fillc[i] = 0;
}

// ---- layer1 GEMM (MFMA bf16, LDS-staged coalesced h1b writes, fused attention dots)
//      || bucket fill (ushort, NT scatter), one dispatch ----
__global__ __launch_bounds__(256) void k_gemm1_fill(const float* __restrict__ x, const unsigned short* __restrict__ w1b,
    const float* __restrict__ atts, const float* __restrict__ attd,
    unsigned short* __restrict__ h1b, float* __restrict__ as1, float* __restrict__ ad1,
    const void* __restrict__ ei, int* __restrict__ fillc, unsigned short* __restrict__ colb){
  __shared__ unsigned short tile[64*HIDC];   // 32 KB: block's 64-node x 256-col bf16 tile
  __shared__ int sflag;
  int tid = threadIdx.x;
  if (blockIdx.x < G1_BLOCKS){
    // ---------------- GEMM1 branch ----------------
    int wv = tid >> 6, l = tid & 63;
    int m0 = blockIdx.x*64 + wv*16;
    int lr = l & 15;
    int lk = l >> 4;

    short8_t a[4];
    int arow = m0 + lr; if (arow > NN-1) arow = NN-1;
    const float* xrow = x + (size_t)arow*INC + lk*8;
    #pragma unroll
    for (int kt = 0; kt < 4; kt++){
      float4 f0 = *(const float4*)(xrow + kt*32);
      float4 f1 = *(const float4*)(xrow + kt*32 + 4);
      short8_t av;
      av[0] = (short)bfr(f0.x); av[1] = (short)bfr(f0.y);
      av[2] = (short)bfr(f0.z); av[3] = (short)bfr(f0.w);
      av[4] = (short)bfr(f1.x); av[5] = (short)bfr(f1.y);
      av[6] = (short)bfr(f1.z); av[7] = (short)bfr(f1.w);
      a[kt] = av;
    }

    const unsigned short* bbase = w1b + (size_t)lr*INC + lk*8;

    for (int h = 0; h < NH; h++){
      float ps[4] = {0.f,0.f,0.f,0.f};
      float pd[4] = {0.f,0.f,0.f,0.f};
      #pragma unroll
      for (int t4 = 0; t4 < 4; t4++){
        int nt = h*4 + t4;
        f32x4_t acc = {0.f,0.f,0.f,0.f};
        #pragma unroll
        for (int kt = 0; kt < 4; kt++){
          short8_t bv = *(const short8_t*)(bbase + (size_t)nt*16*INC + kt*32);
          acc = __builtin_amdgcn_mfma_f32_16x16x32_bf16(a[kt], bv, acc, 0, 0, 0);
        }
        float sa = atts[nt*16 + lr], sd = attd[nt*16 + lr];
        #pragma unroll
        for (int r = 0; r < 4; r++){
          float v = acc[r];
          ps[r] += v*sa; pd[r] += v*sd;
          tile[(wv*16 + lk*4 + r)*HIDC + nt*16 + lr] = bfr(v);
        }
      }
      #pragma unroll
      for (int r = 0; r < 4; r++){
        float p = ps[r], q = pd[r];
        p += __shfl_xor(p, 1); p += __shfl_xor(p, 2); p += __shfl_xor(p, 4); p += __shfl_xor(p, 8);
        q += __shfl_xor(q, 1); q += __shfl_xor(q, 2); q += __shfl_xor(q, 4); q += __shfl_xor(q, 8);
        int node = m0 + lk*4 + r;
        if (lr == 0 && node < NN){ as1[node*NH + h] = p; ad1[node*NH + h] = q; }
      }
    }
    __syncthreads();
    // coalesced writeback: 64 rows x 512B = 2048 float4, 8 per thread
    int nbase = blockIdx.x*64;
    const float4* t4p = (const float4*)tile;
    #pragma unroll
    for (int it = 0; it < 8; it++){
      int idx = it*256 + tid;
      int nrow = idx >> 5;          // 32 float4 per row
      int col4 = idx & 31;
      int node = nbase + nrow;
      if (node < NN) ((float4*)h1b)[(size_t)node*32 + col4] = t4p[idx];
    }
    return;
  }
  // ---------------- fill branch: capped bucket scatter (ushort, non-temporal) ----------------
  int flag = probe_flag(ei, tid, &sflag);
  int e = (blockIdx.x - G1_BLOCKS)*256 + tid;
  if (e >= NE) return;
  int s, d;
  if (flag){
    const long long* p = (const long long*)ei;
    s = (int)p[e]; d = (int)p[NE+e];
  } else {
    const int* p = (const int*)ei;
    s = p[e]; d = p[NE+e];
  }
  s = min(max(s,0),NN-1); d = min(max(d,0),NN-1);
  int pos = atomicAdd(&fillc[d], 1);
  if (pos < CAP) __builtin_nontemporal_store((unsigned short)s, &colb[(size_t)d*CAP + pos]);
}

// ---- layer1 aggregation: fused edge weights, 2 nodes/block, 4 ch/thread, unroll-8,
//      ushort bucket edge list, bf16 out ----
__global__ __launch_bounds__(128) void k_agg1(const unsigned short* __restrict__ h1b,
    const float* __restrict__ as1, const float* __restrict__ ad1,
    const unsigned short* __restrict__ colb, const int* __restrict__ fillc,
    const float* __restrict__ b1, unsigned short* __restrict__ h1a){
  int n = blockIdx.x*2 + (threadIdx.x >> 6);
  if (n >= NN) return;
  int tid = threadIdx.x & 63;
  int head = tid >> 4;
  const uint2* h1q = (const uint2*)h1b;          // row = 64 uint2
  const unsigned short* row = colb + (size_t)n*CAP;

  float adn = ad1[n*NH + head];
  float es_self = __expf(lrelu(as1[n*NH + head] + adn));
  float den = 1e-16f + es_self;
  uint2 v = h1q[(size_t)n*64 + tid];
  float a0 = es_self * bflo(v.x);
  float a1 = es_self * bfhi(v.x);
  float a2 = es_self * bflo(v.y);
  float a3 = es_self * bfhi(v.y);

  int cnt = min(fillc[n], CAP);
  int j = 0;
  for (; j + 7 < cnt; j += 8){
    int s[8]; float w[8]; uint2 g[8];
    #pragma unroll
    for (int u = 0; u < 8; u++) s[u] = row[j+u];
    #pragma unroll
    for (int u = 0; u < 8; u++) g[u] = h1q[(size_t)s[u]*64 + tid];
    #pragma unroll
    for (int u = 0; u < 8; u++) w[u] = as1[s[u]*NH + head];
    #pragma unroll
    for (int u = 0; u < 8; u++) w[u] = __expf(lrelu(w[u] + adn));
    #pragma unroll
    for (int u = 0; u < 8; u++){
      den += w[u];
      a0 += w[u]*bflo(g[u].x); a1 += w[u]*bfhi(g[u].x);
      a2 += w[u]*bflo(g[u].y); a3 += w[u]*bfhi(g[u].y);
    }
  }
  for (; j + 3 < cnt; j += 4){
    int s[4]; float w[4]; uint2 g[4];
    #pragma unroll
    for (int u = 0; u < 4; u++) s[u] = row[j+u];
    #pragma unroll
    for (int u = 0; u < 4; u++) g[u] = h1q[(size_t)s[u]*64 + tid];
    #pragma unroll
    for (int u = 0; u < 4; u++) w[u] = __expf(lrelu(as1[s[u]*NH + head] + adn));
    #pragma unroll
    for (int u = 0; u < 4; u++){
      den += w[u];
      a0 += w[u]*bflo(g[u].x); a1 += w[u]*bfhi(g[u].x);
      a2 += w[u]*bflo(g[u].y); a3 += w[u]*bfhi(g[u].y);
    }
  }
  for (; j < cnt; j++){
    int s0 = row[j];
    uint2 g0 = h1q[(size_t)s0*64 + tid];
    float w0 = __expf(lrelu(as1[s0*NH + head] + adn));
    den += w0;
    a0 += w0*bflo(g0.x); a1 += w0*bfhi(g0.x); a2 += w0*bflo(g0.y); a3 += w0*bfhi(g0.y);
  }

  float4 bb = ((const float4*)b1)[tid];
  float rinv = 1.f / den;
  float o0 = a0*rinv + bb.x;
  float o1 = a1*rinv + bb.y;
  float o2 = a2*rinv + bb.z;
  float o3 = a3*rinv + bb.w;
  o0 = o0 > 0.f ? o0 : (__expf(o0) - 1.f);
  o1 = o1 > 0.f ? o1 : (__expf(o1) - 1.f);
  o2 = o2 > 0.f ? o2 : (__expf(o2) - 1.f);
  o3 = o3 > 0.f ? o3 : (__expf(o3) - 1.f);
  uint2 pkd;
  pkd.x = (unsigned)bfr(o0) | ((unsigned)bfr(o1) << 16);
  pkd.y = (unsigned)bfr(o2) | ((unsigned)bfr(o3) << 16);
  ((uint2*)h1a)[(size_t)n*64 + tid] = pkd;
}

// ---- layer2 GEMM: one node per thread, 128-thread blocks, W2^T in LDS, bf16 in/out ----
__global__ __launch_bounds__(128) void k_gemm2(const unsigned short* __restrict__ h1a, const float* __restrict__ W2,
    const float* __restrict__ atts2, const float* __restrict__ attd2,
    unsigned* __restrict__ h2b, float* __restrict__ a2s, float* __restrict__ a2d){
  __shared__ float W2t[HIDC*OUTC];   // [k][c] transposed, 40 KB
  __shared__ float sA[OUTC], sD[OUTC];
  int tid = threadIdx.x;
  #pragma unroll
  for (int it = 0; it < (OUTC*HIDC)/128; it++){
    int idx = it*128 + tid;
    int c = idx >> 8, k = idx & 255;
    W2t[k*OUTC + c] = W2[idx];
  }
  if (tid < OUTC){ sA[tid] = atts2[tid]; sD[tid] = attd2[tid]; }
  __syncthreads();

  int n = blockIdx.x*128 + tid;
  if (n >= NN) return;

  float acc[OUTC];
  #pragma unroll
  for (int c = 0; c < OUTC; c++) acc[c] = 0.f;

  const uint2* x2p = (const uint2*)(h1a + (size_t)n*HIDC);
  const float4* w4p = (const float4*)W2t;
  #pragma unroll 2
  for (int k4 = 0; k4 < HIDC/4; k4++){
    uint2 xu = x2p[k4];
    float xk[4] = { bflo(xu.x), bfhi(xu.x), bflo(xu.y), bfhi(xu.y) };
    #pragma unroll
    for (int kk = 0; kk < 4; kk++){
      #pragma unroll
      for (int c4 = 0; c4 < OUTC/4; c4++){
        float4 wv = w4p[(k4*4 + kk)*(OUTC/4) + c4];
        acc[c4*4+0] += xk[kk]*wv.x;
        acc[c4*4+1] += xk[kk]*wv.y;
        acc[c4*4+2] += xk[kk]*wv.z;
        acc[c4*4+3] += xk[kk]*wv.w;
      }
    }
  }

  float s2 = 0.f, d2 = 0.f;
  #pragma unroll
  for (int c = 0; c < OUTC; c++){ s2 += acc[c]*sA[c]; d2 += acc[c]*sD[c]; }

  unsigned* h2row = h2b + (size_t)n*(OUTC/2);
  #pragma unroll
  for (int c2 = 0; c2 < OUTC/2; c2++)
    h2row[c2] = (unsigned)bfr(acc[c2*2]) | ((unsigned)bfr(acc[c2*2+1]) << 16);
  a2s[n] = s2; a2d[n] = d2;
}

// ---- layer2 aggregation: fused edge weights, uint2 lanes (10/node), 6 nodes/wave, 12/block ----
__global__ __launch_bounds__(128) void k_agg2(const unsigned* __restrict__ h2b, const float* __restrict__ a2s,
    const float* __restrict__ a2d, const unsigned short* __restrict__ colb, const int* __restrict__ fillc,
    const float* __restrict__ b2, float* __restrict__ out){
  int lane = threadIdx.x & 63;
  int wave = threadIdx.x >> 6;
  int sub = lane / 10, li = lane % 10;
  int n = blockIdx.x*12 + wave*6 + sub;
  bool valid = (sub < 6) && (n < NN);
  int nn = valid ? n : 0;
  const uint2* h2q = (const uint2*)h2b;
  const unsigned short* row = colb + (size_t)nn*CAP;

  float a2dn = a2d[nn];
  float e = __expf(lrelu(a2s[nn] + a2dn));
  float den = 1e-16f + e;
  uint2 v = h2q[(size_t)nn*10 + li];
  float c0 = e * bflo(v.x);
  float c1 = e * bfhi(v.x);
  float c2 = e * bflo(v.y);
  float c3 = e * bfhi(v.y);

  int cnt = valid ? min(fillc[nn], CAP) : 0;
  int j = 0;
  for (; j + 3 < cnt; j += 4){
    int s[4]; float w[4]; uint2 g[4];
    #pragma unroll
    for (int u = 0; u < 4; u++) s[u] = row[j+u];
    #pragma unroll
    for (int u = 0; u < 4; u++) g[u] = h2q[(size_t)s[u]*10 + li];
    #pragma unroll
    for (int u = 0; u < 4; u++) w[u] = a2s[s[u]];
    #pragma unroll
    for (int u = 0; u < 4; u++) w[u] = __expf(lrelu(w[u] + a2dn));
    #pragma unroll
    for (int u = 0; u < 4; u++){
      den += w[u];
      c0 += w[u]*bflo(g[u].x); c1 += w[u]*bfhi(g[u].x);
      c2 += w[u]*bflo(g[u].y); c3 += w[u]*bfhi(g[u].y);
    }
  }
  for (; j < cnt; j++){
    int s0 = row[j];
    uint2 g0 = h2q[(size_t)s0*10 + li];
    float w0 = __expf(lrelu(a2s[s0] + a2dn));
    den += w0;
    c0 += w0*bflo(g0.x); c1 += w0*bfhi(g0.x); c2 += w0*bflo(g0.y); c3 += w0*bfhi(g0.y);
  }

  if (valid){
    float rinv = 1.f / den;
    float4 bb = ((const float4*)b2)[li];
    float4 o;
    o.x = c0*rinv + bb.x;
    o.y = c1*rinv + bb.y;
    o.z = c2*rinv + bb.z;
    o.w = c3*rinv + bb.w;
    ((float4*)(out + (size_t)n*OUTC))[li] = o;
  }
}

extern "C" void kernel_launch(void* const* d_in, const int* in_sizes, int n_in,
                              void* d_out, int out_size, void* d_ws, size_t ws_size,
                              hipStream_t stream){
  const float* x    = (const float*)d_in[0];
  const void*  ei   = d_in[1];
  const float* W1   = (const float*)d_in[2];
  const float* as1w = (const float*)d_in[3];
  const float* ad1w = (const float*)d_in[4];
  const float* b1   = (const float*)d_in[5];
  const float* W2   = (const float*)d_in[6];
  const float* as2w = (const float*)d_in[7];
  const float* ad2w = (const float*)d_in[8];
  const float* b2   = (const float*)d_in[9];
  float* out = (float*)d_out;

  char* base = (char*)d_ws;
  size_t off = 0;
  auto alloc = [&](size_t bytes)->char*{ char* r = base + off; off += (bytes + 255) & ~(size_t)255; return r; };
  int* fillc  = (int*)alloc((size_t)NN*sizeof(int));
  unsigned short* colb = (unsigned short*)alloc((size_t)NN*CAP*sizeof(unsigned short));
  unsigned short* w1b = (unsigned short*)alloc((size_t)HIDC*INC*sizeof(unsigned short));
  unsigned short* h1b = (unsigned short*)alloc((size_t)NN*HIDC*sizeof(unsigned short));
  unsigned short* h1a = (unsigned short*)alloc((size_t)NN*HIDC*sizeof(unsigned short));
  float* as1  = (float*)alloc((size_t)NN*NH*sizeof(float));
  float* ad1  = (float*)alloc((size_t)NN*NH*sizeof(float));
  unsigned* h2b = (unsigned*)alloc((size_t)NN*(OUTC/2)*sizeof(unsigned));
  float* a2s  = (float*)alloc((size_t)NN*sizeof(float));
  float* a2d  = (float*)alloc((size_t)NN*sizeof(float));

  k_prep<<<CVT_BLOCKS + FZ_BLOCKS, 256, 0, stream>>>(W1, w1b, fillc);
  k_gemm1_fill<<<G1_BLOCKS + GE_BLOCKS, 256, 0, stream>>>(x, w1b, as1w, ad1w, h1b, as1, ad1,
                                                          ei, fillc, colb);
  k_agg1<<<(NN + 1)/2, 128, 0, stream>>>(h1b, as1, ad1, colb, fillc, b1, h1a);
  k_gemm2<<<(NN + 127)/128, 128, 0, stream>>>(h1a, W2, as2w, ad2w, h2b, a2s, a2d);
  k_agg2<<<(NN + 11)/12, 128, 0, stream>>>(h2b, a2s, a2d, colb, fillc, b2, out);
}

// Round 20
// 193.470 us; speedup vs baseline: 1.2150x; 1.2150x over previous
//
#include <hip/hip_runtime.h>
#include <hip/hip_bf16.h>
#include <cstdint>
#include <cstddef>

#define NN 50000
#define NE 800000
#define INC 128
#define HIDC 256
#define NH 4
#define OUTC 40
#define CAP 64   // bucket capacity; deg ~ Poisson(16), P(>=64) ~ e^-125

#define GE_BLOCKS ((NE + 255)/256)          // 3125
#define CVT_BLOCKS ((HIDC*INC/4 + 255)/256) // 32
#define FZ_BLOCKS ((NN + 255)/256)          // 196
#define G1_BLOCKS ((NN + 63)/64)            // 782

typedef __attribute__((ext_vector_type(8))) short short8_t;
typedef __attribute__((ext_vector_type(4))) float f32x4_t;

__device__ __forceinline__ float lrelu(float x){ return x > 0.f ? x : 0.2f*x; }
__device__ __forceinline__ unsigned short bfr(float f){
  __hip_bfloat16 h = __float2bfloat16(f);
  return *reinterpret_cast<unsigned short*>(&h);
}
__device__ __forceinline__ float bflo(unsigned u){ return __uint_as_float(u << 16); }
__device__ __forceinline__ float bfhi(unsigned u){ return __uint_as_float(u & 0xffff0000u); }

// Per-block dtype probe: int64 view of int32 pairs gives values >= 2^32 at some
// of 64 strided samples. Wave 0 probes, result broadcast via LDS.
__device__ __forceinline__ int probe_flag(const void* ei, int tid, int* sflag){
  if (tid < 64){
    long long v = ((const long long*)ei)[(long long)tid * (NE/64)];
    bool ok = (v >= 0) && (v < NN);
    unsigned long long m = __ballot(ok);
    if (tid == 0) *sflag = (m == 0xFFFFFFFFFFFFFFFFull) ? 1 : 0;
  }
  __syncthreads();
  return *sflag;
}

// ---- prep: W1->bf16 convert + zero bucket counters, one dispatch ----
__global__ __launch_bounds__(256) void k_prep(const float* __restrict__ W1, unsigned short* __restrict__ w1b,
                                              int* __restrict__ fillc){
  int tid = threadIdx.x;
  if (blockIdx.x < CVT_BLOCKS){
    int i = blockIdx.x*256 + tid;
    if (i < HIDC*INC/4){
      float4 v = ((const float4*)W1)[i];
      ushort4 o;
      o.x = bfr(v.x); o.y = bfr(v.y); o.z = bfr(v.z); o.w = bfr(v.w);
      ((ushort4*)w1b)[i] = o;
    }
    return;
  }
  int i = (blockIdx.x - CVT_BLOCKS)*256 + tid;
  if (i < NN) fillc[i] = 0;
}

// ---- layer1 GEMM (MFMA bf16, direct h1b stores, fused attention dots)
//      || bucket fill (ushort, NT scatter), one dispatch ----
__global__ __launch_bounds__(256) void k_gemm1_fill(const float* __restrict__ x, const unsigned short* __restrict__ w1b,
    const float* __restrict__ atts, const float* __restrict__ attd,
    unsigned short* __restrict__ h1b, float* __restrict__ as1, float* __restrict__ ad1,
    const void* __restrict__ ei, int* __restrict__ fillc, unsigned short* __restrict__ colb){
  int tid = threadIdx.x;
  if (blockIdx.x < G1_BLOCKS){
    // ---------------- GEMM1 branch ----------------
    int wv = tid >> 6, l = tid & 63;
    int m0 = blockIdx.x*64 + wv*16;
    int lr = l & 15;
    int lk = l >> 4;

    short8_t a[4];
    int arow = m0 + lr; if (arow > NN-1) arow = NN-1;
    const float* xrow = x + (size_t)arow*INC + lk*8;
    #pragma unroll
    for (int kt = 0; kt < 4; kt++){
      float4 f0 = *(const float4*)(xrow + kt*32);
      float4 f1 = *(const float4*)(xrow + kt*32 + 4);
      short8_t av;
      av[0] = (short)bfr(f0.x); av[1] = (short)bfr(f0.y);
      av[2] = (short)bfr(f0.z); av[3] = (short)bfr(f0.w);
      av[4] = (short)bfr(f1.x); av[5] = (short)bfr(f1.y);
      av[6] = (short)bfr(f1.z); av[7] = (short)bfr(f1.w);
      a[kt] = av;
    }

    const unsigned short* bbase = w1b + (size_t)lr*INC + lk*8;

    for (int h = 0; h < NH; h++){
      float ps[4] = {0.f,0.f,0.f,0.f};
      float pd[4] = {0.f,0.f,0.f,0.f};
      #pragma unroll
      for (int t4 = 0; t4 < 4; t4++){
        int nt = h*4 + t4;
        f32x4_t acc = {0.f,0.f,0.f,0.f};
        #pragma unroll
        for (int kt = 0; kt < 4; kt++){
          short8_t bv = *(const short8_t*)(bbase + (size_t)nt*16*INC + kt*32);
          acc = __builtin_amdgcn_mfma_f32_16x16x32_bf16(a[kt], bv, acc, 0, 0, 0);
        }
        float sa = atts[nt*16 + lr], sd = attd[nt*16 + lr];
        #pragma unroll
        for (int r = 0; r < 4; r++){
          float v = acc[r];
          ps[r] += v*sa; pd[r] += v*sd;
          int node = m0 + lk*4 + r;
          if (node < NN) h1b[(size_t)node*HIDC + nt*16 + lr] = bfr(v);
        }
      }
      #pragma unroll
      for (int r = 0; r < 4; r++){
        float p = ps[r], q = pd[r];
        p += __shfl_xor(p, 1); p += __shfl_xor(p, 2); p += __shfl_xor(p, 4); p += __shfl_xor(p, 8);
        q += __shfl_xor(q, 1); q += __shfl_xor(q, 2); q += __shfl_xor(q, 4); q += __shfl_xor(q, 8);
        int node = m0 + lk*4 + r;
        if (lr == 0 && node < NN){ as1[node*NH + h] = p; ad1[node*NH + h] = q; }
      }
    }
    return;
  }
  // ---------------- fill branch: capped bucket scatter (ushort, non-temporal) ----------------
  __shared__ int sflag;
  int flag = probe_flag(ei, tid, &sflag);
  int e = (blockIdx.x - G1_BLOCKS)*256 + tid;
  if (e >= NE) return;
  int s, d;
  if (flag){
    const long long* p = (const long long*)ei;
    s = (int)p[e]; d = (int)p[NE+e];
  } else {
    const int* p = (const int*)ei;
    s = p[e]; d = p[NE+e];
  }
  s = min(max(s,0),NN-1); d = min(max(d,0),NN-1);
  int pos = atomicAdd(&fillc[d], 1);
  if (pos < CAP) __builtin_nontemporal_store((unsigned short)s, &colb[(size_t)d*CAP + pos]);
}

// ---- layer1 aggregation: fused edge weights, 2 nodes/block, 4 ch/thread, unroll-8,
//      ushort bucket edge list, bf16 out ----
__global__ __launch_bounds__(128) void k_agg1(const unsigned short* __restrict__ h1b,
    const float* __restrict__ as1, const float* __restrict__ ad1,
    const unsigned short* __restrict__ colb, const int* __restrict__ fillc,
    const float* __restrict__ b1, unsigned short* __restrict__ h1a){
  int n = blockIdx.x*2 + (threadIdx.x >> 6);
  if (n >= NN) return;
  int tid = threadIdx.x & 63;
  int head = tid >> 4;
  const uint2* h1q = (const uint2*)h1b;          // row = 64 uint2
  const unsigned short* row = colb + (size_t)n*CAP;

  float adn = ad1[n*NH + head];
  float es_self = __expf(lrelu(as1[n*NH + head] + adn));
  float den = 1e-16f + es_self;
  uint2 v = h1q[(size_t)n*64 + tid];
  float a0 = es_self * bflo(v.x);
  float a1 = es_self * bfhi(v.x);
  float a2 = es_self * bflo(v.y);
  float a3 = es_self * bfhi(v.y);

  int cnt = min(fillc[n], CAP);
  int j = 0;
  for (; j + 7 < cnt; j += 8){
    int s[8]; float w[8]; uint2 g[8];
    #pragma unroll
    for (int u = 0; u < 8; u++) s[u] = row[j+u];
    #pragma unroll
    for (int u = 0; u < 8; u++) g[u] = h1q[(size_t)s[u]*64 + tid];
    #pragma unroll
    for (int u = 0; u < 8; u++) w[u] = as1[s[u]*NH + head];
    #pragma unroll
    for (int u = 0; u < 8; u++) w[u] = __expf(lrelu(w[u] + adn));
    #pragma unroll
    for (int u = 0; u < 8; u++){
      den += w[u];
      a0 += w[u]*bflo(g[u].x); a1 += w[u]*bfhi(g[u].x);
      a2 += w[u]*bflo(g[u].y); a3 += w[u]*bfhi(g[u].y);
    }
  }
  for (; j + 3 < cnt; j += 4){
    int s[4]; float w[4]; uint2 g[4];
    #pragma unroll
    for (int u = 0; u < 4; u++) s[u] = row[j+u];
    #pragma unroll
    for (int u = 0; u < 4; u++) g[u] = h1q[(size_t)s[u]*64 + tid];
    #pragma unroll
    for (int u = 0; u < 4; u++) w[u] = __expf(lrelu(as1[s[u]*NH + head] + adn));
    #pragma unroll
    for (int u = 0; u < 4; u++){
      den += w[u];
      a0 += w[u]*bflo(g[u].x); a1 += w[u]*bfhi(g[u].x);
      a2 += w[u]*bflo(g[u].y); a3 += w[u]*bfhi(g[u].y);
    }
  }
  for (; j < cnt; j++){
    int s0 = row[j];
    uint2 g0 = h1q[(size_t)s0*64 + tid];
    float w0 = __expf(lrelu(as1[s0*NH + head] + adn));
    den += w0;
    a0 += w0*bflo(g0.x); a1 += w0*bfhi(g0.x); a2 += w0*bflo(g0.y); a3 += w0*bfhi(g0.y);
  }

  float4 bb = ((const float4*)b1)[tid];
  float rinv = 1.f / den;
  float o0 = a0*rinv + bb.x;
  float o1 = a1*rinv + bb.y;
  float o2 = a2*rinv + bb.z;
  float o3 = a3*rinv + bb.w;
  o0 = o0 > 0.f ? o0 : (__expf(o0) - 1.f);
  o1 = o1 > 0.f ? o1 : (__expf(o1) - 1.f);
  o2 = o2 > 0.f ? o2 : (__expf(o2) - 1.f);
  o3 = o3 > 0.f ? o3 : (__expf(o3) - 1.f);
  uint2 pkd;
  pkd.x = (unsigned)bfr(o0) | ((unsigned)bfr(o1) << 16);
  pkd.y = (unsigned)bfr(o2) | ((unsigned)bfr(o3) << 16);
  ((uint2*)h1a)[(size_t)n*64 + tid] = pkd;
}

// ---- layer2 GEMM: one node per thread, 128-thread blocks, W2^T in LDS, bf16 in/out ----
__global__ __launch_bounds__(128) void k_gemm2(const unsigned short* __restrict__ h1a, const float* __restrict__ W2,
    const float* __restrict__ atts2, const float* __restrict__ attd2,
    unsigned* __restrict__ h2b, float* __restrict__ a2s, float* __restrict__ a2d){
  __shared__ float W2t[HIDC*OUTC];   // [k][c] transposed, 40 KB
  __shared__ float sA[OUTC], sD[OUTC];
  int tid = threadIdx.x;
  #pragma unroll
  for (int it = 0; it < (OUTC*HIDC)/128; it++){
    int idx = it*128 + tid;
    int c = idx >> 8, k = idx & 255;
    W2t[k*OUTC + c] = W2[idx];
  }
  if (tid < OUTC){ sA[tid] = atts2[tid]; sD[tid] = attd2[tid]; }
  __syncthreads();

  int n = blockIdx.x*128 + tid;
  if (n >= NN) return;

  float acc[OUTC];
  #pragma unroll
  for (int c = 0; c < OUTC; c++) acc[c] = 0.f;

  const uint2* x2p = (const uint2*)(h1a + (size_t)n*HIDC);
  const float4* w4p = (const float4*)W2t;
  #pragma unroll 2
  for (int k4 = 0; k4 < HIDC/4; k4++){
    uint2 xu = x2p[k4];
    float xk[4] = { bflo(xu.x), bfhi(xu.x), bflo(xu.y), bfhi(xu.y) };
    #pragma unroll
    for (int kk = 0; kk < 4; kk++){
      #pragma unroll
      for (int c4 = 0; c4 < OUTC/4; c4++){
        float4 wv = w4p[(k4*4 + kk)*(OUTC/4) + c4];
        acc[c4*4+0] += xk[kk]*wv.x;
        acc[c4*4+1] += xk[kk]*wv.y;
        acc[c4*4+2] += xk[kk]*wv.z;
        acc[c4*4+3] += xk[kk]*wv.w;
      }
    }
  }

  float s2 = 0.f, d2 = 0.f;
  #pragma unroll
  for (int c = 0; c < OUTC; c++){ s2 += acc[c]*sA[c]; d2 += acc[c]*sD[c]; }

  unsigned* h2row = h2b + (size_t)n*(OUTC/2);
  #pragma unroll
  for (int c2 = 0; c2 < OUTC/2; c2++)
    h2row[c2] = (unsigned)bfr(acc[c2*2]) | ((unsigned)bfr(acc[c2*2+1]) << 16);
  a2s[n] = s2; a2d[n] = d2;
}

// ---- layer2 aggregation: fused edge weights, uint2 lanes (10/node), 6 nodes/wave, 12/block ----
__global__ __launch_bounds__(128) void k_agg2(const unsigned* __restrict__ h2b, const float* __restrict__ a2s,
    const float* __restrict__ a2d, const unsigned short* __restrict__ colb, const int* __restrict__ fillc,
    const float* __restrict__ b2, float* __restrict__ out){
  int lane = threadIdx.x & 63;
  int wave = threadIdx.x >> 6;
  int sub = lane / 10, li = lane % 10;
  int n = blockIdx.x*12 + wave*6 + sub;
  bool valid = (sub < 6) && (n < NN);
  int nn = valid ? n : 0;
  const uint2* h2q = (const uint2*)h2b;
  const unsigned short* row = colb + (size_t)nn*CAP;

  float a2dn = a2d[nn];
  float e = __expf(lrelu(a2s[nn] + a2dn));
  float den = 1e-16f + e;
  uint2 v = h2q[(size_t)nn*10 + li];
  float c0 = e * bflo(v.x);
  float c1 = e * bfhi(v.x);
  float c2 = e * bflo(v.y);
  float c3 = e * bfhi(v.y);

  int cnt = valid ? min(fillc[nn], CAP) : 0;
  int j = 0;
  for (; j + 3 < cnt; j += 4){
    int s[4]; float w[4]; uint2 g[4];
    #pragma unroll
    for (int u = 0; u < 4; u++) s[u] = row[j+u];
    #pragma unroll
    for (int u = 0; u < 4; u++) g[u] = h2q[(size_t)s[u]*10 + li];
    #pragma unroll
    for (int u = 0; u < 4; u++) w[u] = a2s[s[u]];
    #pragma unroll
    for (int u = 0; u < 4; u++) w[u] = __expf(lrelu(w[u] + a2dn));
    #pragma unroll
    for (int u = 0; u < 4; u++){
      den += w[u];
      c0 += w[u]*bflo(g[u].x); c1 += w[u]*bfhi(g[u].x);
      c2 += w[u]*bflo(g[u].y); c3 += w[u]*bfhi(g[u].y);
    }
  }
  for (; j < cnt; j++){
    int s0 = row[j];
    uint2 g0 = h2q[(size_t)s0*10 + li];
    float w0 = __expf(lrelu(a2s[s0] + a2dn));
    den += w0;
    c0 += w0*bflo(g0.x); c1 += w0*bfhi(g0.x); c2 += w0*bflo(g0.y); c3 += w0*bfhi(g0.y);
  }

  if (valid){
    float rinv = 1.f / den;
    float4 bb = ((const float4*)b2)[li];
    float4 o;
    o.x = c0*rinv + bb.x;
    o.y = c1*rinv + bb.y;
    o.z = c2*rinv + bb.z;
    o.w = c3*rinv + bb.w;
    ((float4*)(out + (size_t)n*OUTC))[li] = o;
  }
}

extern "C" void kernel_launch(void* const* d_in, const int* in_sizes, int n_in,
                              void* d_out, int out_size, void* d_ws, size_t ws_size,
                              hipStream_t stream){
  const float* x    = (const float*)d_in[0];
  const void*  ei   = d_in[1];
  const float* W1   = (const float*)d_in[2];
  const float* as1w = (const float*)d_in[3];
  const float* ad1w = (const float*)d_in[4];
  const float* b1   = (const float*)d_in[5];
  const float* W2   = (const float*)d_in[6];
  const float* as2w = (const float*)d_in[7];
  const float* ad2w = (const float*)d_in[8];
  const float* b2   = (const float*)d_in[9];
  float* out = (float*)d_out;

  char* base = (char*)d_ws;
  size_t off = 0;
  auto alloc = [&](size_t bytes)->char*{ char* r = base + off; off += (bytes + 255) & ~(size_t)255; return r; };
  int* fillc  = (int*)alloc((size_t)NN*sizeof(int));
  unsigned short* colb = (unsigned short*)alloc((size_t)NN*CAP*sizeof(unsigned short));
  unsigned short* w1b = (unsigned short*)alloc((size_t)HIDC*INC*sizeof(unsigned short));
  unsigned short* h1b = (unsigned short*)alloc((size_t)NN*HIDC*sizeof(unsigned short));
  unsigned short* h1a = (unsigned short*)alloc((size_t)NN*HIDC*sizeof(unsigned short));
  float* as1  = (float*)alloc((size_t)NN*NH*sizeof(float));
  float* ad1  = (float*)alloc((size_t)NN*NH*sizeof(float));
  unsigned* h2b = (unsigned*)alloc((size_t)NN*(OUTC/2)*sizeof(unsigned));
  float* a2s  = (float*)alloc((size_t)NN*sizeof(float));
  float* a2d  = (float*)alloc((size_t)NN*sizeof(float));

  k_prep<<<CVT_BLOCKS + FZ_BLOCKS, 256, 0, stream>>>(W1, w1b, fillc);
  k_gemm1_fill<<<G1_BLOCKS + GE_BLOCKS, 256, 0, stream>>>(x, w1b, as1w, ad1w, h1b, as1, ad1,
                                                          ei, fillc, colb);
  k_agg1<<<(NN + 1)/2, 128, 0, stream>>>(h1b, as1, ad1, colb, fillc, b1, h1a);
  k_gemm2<<<(NN + 127)/128, 128, 0, stream>>>(h1a, W2, as2w, ad2w, h2b, a2s, a2d);
  k_agg2<<<(NN + 11)/12, 128, 0, stream>>>(h2b, a2s, a2d, colb, fillc, b2, out);
}